// Round 4
// baseline (457.573 us; speedup 1.0000x reference)
//
#include <hip/hip_runtime.h>
#include <math.h>

#define DIM 2048
#define SLOTS 256
#define TSTEPS 64

typedef unsigned short u16;
typedef __bf16 bf16x8 __attribute__((ext_vector_type(8)));
typedef float f32x4 __attribute__((ext_vector_type(4)));

union FragU { unsigned u[4]; bf16x8 v; };

__device__ __forceinline__ float bf2f(u16 h){
    union { unsigned u; float f; } v; v.u = ((unsigned)h) << 16; return v.f;
}
// round-to-nearest-even f32 -> bf16
__device__ __forceinline__ u16 f2bf(float f){
    union { float f; unsigned u; } v; v.f = f;
    unsigned r = v.u + 0x7fffu + ((v.u >> 16) & 1u);
    return (u16)(r >> 16);
}
__device__ __forceinline__ float sigmoidf_(float x){ return 1.0f / (1.0f + __expf(-x)); }

__device__ __forceinline__ float ldf(const void* p, size_t i, int isf){
    return isf ? ((const float*)p)[i] : bf2f(((const u16*)p)[i]);
}

// load 8 consecutive floats (i multiple of 8) from f32 or bf16 buffer
__device__ __forceinline__ void load8f(const void* p, size_t i, int isf, float* o){
    if (isf){
        float4 a = *(const float4*)((const float*)p + i);
        float4 b = *(const float4*)((const float*)p + i + 4);
        o[0]=a.x; o[1]=a.y; o[2]=a.z; o[3]=a.w;
        o[4]=b.x; o[5]=b.y; o[6]=b.z; o[7]=b.w;
    } else {
        uint4 a = *(const uint4*)((const u16*)p + i);
        const unsigned* w = reinterpret_cast<const unsigned*>(&a);
        #pragma unroll
        for (int j = 0; j < 4; ++j){
            o[2*j]   = bf2f((u16)(w[j] & 0xffffu));
            o[2*j+1] = bf2f((u16)(w[j] >> 16));
        }
    }
}

// split 8 f32 into bf16 hi + bf16 lo fragments
__device__ __forceinline__ void split8(const float* x, bf16x8& hi, bf16x8& lo){
    FragU H, L;
    #pragma unroll
    for (int p = 0; p < 4; ++p){
        float v0 = x[2*p], v1 = x[2*p+1];
        u16 h0 = f2bf(v0), h1 = f2bf(v1);
        H.u[p] = (unsigned)h0 | ((unsigned)h1 << 16);
        u16 l0 = f2bf(v0 - bf2f(h0)), l1 = f2bf(v1 - bf2f(h1));
        L.u[p] = (unsigned)l0 | ((unsigned)l1 << 16);
    }
    hi = H.v; lo = L.v;
}

__device__ __forceinline__ f32x4 mfma16(bf16x8 a, bf16x8 b, f32x4 c){
    return __builtin_amdgcn_mfma_f32_16x16x32_bf16(a, b, c, 0, 0, 0);
}

// ---------------- dtype detection ----------------
// flags[0]=1 if float inputs are f32 (else bf16); flags[1]=1 if idx is int64
__global__ void detect_k(const unsigned* __restrict__ W1w, const int* __restrict__ idxw,
                         int* __restrict__ flags)
{
    __shared__ int weird_s, nz_s;
    if (threadIdx.x == 0){ weird_s = 0; nz_s = 0; }
    __syncthreads();
    int weird = 0;
    for (int i = threadIdx.x; i < 1024; i += 256){
        unsigned lo = W1w[i] & 0xffffu;          // low half-word of each u32
        int e = (int)((lo >> 7) & 0xffu);        // bf16 exponent field
        if (e == 0xff || e < 70 || e > 185) weird++;   // impossible for genuine W1 bf16 values
    }
    int nz = 0;
    if (threadIdx.x < 32 && idxw[2 * threadIdx.x + 1] != 0) nz = 1;
    atomicAdd(&weird_s, weird);
    atomicAdd(&nz_s, nz);
    __syncthreads();
    if (threadIdx.x == 0){
        flags[0] = (weird_s > 100) ? 1 : 0;
        flags[1] = (nz_s == 0) ? 1 : 0;
    }
}

// ---------------- MFMA D-layout runtime calibration (kept: label-invariance guard) -------
__global__ void calib_k(unsigned short* __restrict__ tbl)
{
    const int lane = threadIdx.x;          // 64 threads = 1 wave
    const u16 oneb = 0x3F80;               // 1.0 bf16
    const u16 lb = f2bf((float)((lane & 15) + 1));  // exact for 1..16
    FragU O, L;
    #pragma unroll
    for (int p = 0; p < 4; ++p){
        O.u[p] = ((unsigned)oneb) | (((unsigned)oneb) << 16);
        L.u[p] = ((unsigned)lb)   | (((unsigned)lb)   << 16);
    }
    f32x4 z = {0.f, 0.f, 0.f, 0.f};
    f32x4 dj = mfma16(O.v, L.v, z);   // value = 32*(B-index+1) -> j_local
    f32x4 dt = mfma16(L.v, O.v, z);   // value = 32*(A-index+1) -> t_local
    #pragma unroll
    for (int r = 0; r < 4; ++r){
        int jl = (int)(dj[r] * (1.0f/32.0f) + 0.5f) - 1;
        int tl = (int)(dt[r] * (1.0f/32.0f) + 0.5f) - 1;
        tbl[lane * 4 + r] = (unsigned short)((tl & 15) | ((jl & 15) << 8));
    }
}

// ---------------- PREP: A0[t][k] = traces[idx[t]][k] + 0.01*noise[t][k] (fp32 out) -------
__global__ __launch_bounds__(256)
void prep(const void* __restrict__ traces, const void* __restrict__ noise,
          const int* __restrict__ idxw, const int* __restrict__ flags,
          float* __restrict__ A0)
{
    const int isf = flags[0];
    const int t = blockIdx.x;
    long row;
    if (flags[1]) row = (long)idxw[2 * t];   // int64 low word
    else          row = (long)idxw[t];
    const int k = threadIdx.x * 8;
    float a[8], b[8];
    load8f(traces, (size_t)row * DIM + k, isf, a);
    load8f(noise,  (size_t)t   * DIM + k, isf, b);
    float* o = A0 + (size_t)t * DIM + k;
    #pragma unroll
    for (int j = 0; j < 8; ++j) o[j] = fmaf(0.01f, b[j], a[j]);
}

// ---------------- MFMA skinny GEMM core: 16x16 D-tile = A(16 rows) x W(16 rows)^T --------
__device__ __forceinline__ f32x4 gemm_core(const float* __restrict__ A, const void* __restrict__ W,
                                           int isf, int j0, int lane, int wave)
{
    const int n = lane & 15, q = lane >> 4;
    const float* ap = A + (size_t)(wave * 16 + n) * DIM + q * 8;
    const size_t wb = (size_t)(j0 + n) * DIM + q * 8;
    f32x4 acc = {0.f, 0.f, 0.f, 0.f};
    if (isf){
        const float* wp = (const float*)W + wb;
        #pragma unroll 4
        for (int k = 0; k < DIM; k += 32){
            float a8[8], w8[8];
            *(float4*)(a8)     = *(const float4*)(ap);
            *(float4*)(a8 + 4) = *(const float4*)(ap + 4);
            *(float4*)(w8)     = *(const float4*)(wp);
            *(float4*)(w8 + 4) = *(const float4*)(wp + 4);
            bf16x8 ah, al, wh, wl;
            split8(a8, ah, al);
            split8(w8, wh, wl);
            acc = mfma16(ah, wh, acc);
            acc = mfma16(al, wh, acc);
            acc = mfma16(ah, wl, acc);
            ap += 32; wp += 32;
        }
    } else {
        const u16* wp = (const u16*)W + wb;
        #pragma unroll 4
        for (int k = 0; k < DIM; k += 32){
            float a8[8];
            *(float4*)(a8)     = *(const float4*)(ap);
            *(float4*)(a8 + 4) = *(const float4*)(ap + 4);
            bf16x8 ah, al;
            split8(a8, ah, al);
            bf16x8 wh = *(const bf16x8*)(wp);
            acc = mfma16(ah, wh, acc);
            acc = mfma16(al, wh, acc);
            ap += 32; wp += 32;
        }
    }
    return acc;
}

// MODE 0: relu(acc+b)           -> h   (fp32)
// MODE 1: acc+b                 -> x   (fp32)
// MODE 2: sigmoid(acc+b)*volt   -> lv  (fp32)
// MODE 3: X * sigmoid(acc+b)    -> gated (fp32)
template<int MODE>
__global__ __launch_bounds__(256)
void gemm_stage(const float* __restrict__ A, const void* __restrict__ W,
                const void* __restrict__ bias,
                const void* __restrict__ vw, const void* __restrict__ vb,
                const float* __restrict__ Xbuf, const int* __restrict__ flags,
                const unsigned short* __restrict__ tbl,
                float* __restrict__ outb)
{
    const int isf = flags[0];
    const int lane = threadIdx.x & 63;
    const int wave = threadIdx.x >> 6;
    const int j0 = blockIdx.x * 16;
    f32x4 acc = gemm_core(A, W, isf, j0, lane, wave);
    #pragma unroll
    for (int i = 0; i < 4; ++i){
        const unsigned short tj = tbl[lane * 4 + i];
        const int t = wave * 16 + (tj & 15);
        const int j = j0 + ((tj >> 8) & 15);
        float v = acc[i] + ldf(bias, j, isf);
        if (MODE == 0){
            v = fmaxf(v, 0.f);
        } else if (MODE == 2){
            float lig = sigmoidf_(v);
            // cos(phase - pi) = -cos(2*pi*FREQ*DT*(t+1))
            float ps = -cosf(0.37699111843077515f * (float)(t + 1));
            float volt = sigmoidf_(fmaf(ps, ldf(vw, j, isf), ldf(vb, j, isf)));
            v = lig * volt;
        } else if (MODE == 3){
            float gate = sigmoidf_(v);
            v = Xbuf[(size_t)t * DIM + j] * gate;
        }
        outb[(size_t)t * DIM + j] = v;
    }
}

// erase = sigmoid(g@We^T+be), add = g@Wad^T+bad, logits = g@Wa^T+ba   (all fp32)
__global__ __launch_bounds__(256)
void gemm_heads(const float* __restrict__ G,
                const void* __restrict__ We,  const void* __restrict__ be,
                const void* __restrict__ Wad, const void* __restrict__ bad_,
                const void* __restrict__ Wa,  const void* __restrict__ ba,
                const int* __restrict__ flags, const unsigned short* __restrict__ tbl,
                float* __restrict__ erase, float* __restrict__ addv, float* __restrict__ logits)
{
    const int isf = flags[0];
    const int lane = threadIdx.x & 63;
    const int wave = threadIdx.x >> 6;
    const int b = blockIdx.x;
    const void* W; const void* bias; float* out; int j0; int ostride; int do_sig;
    if (b < 128)      { W = We;  bias = be;   out = erase;  j0 = b * 16;         ostride = DIM;   do_sig = 1; }
    else if (b < 256) { W = Wad; bias = bad_; out = addv;   j0 = (b - 128) * 16; ostride = DIM;   do_sig = 0; }
    else              { W = Wa;  bias = ba;   out = logits; j0 = (b - 256) * 16; ostride = SLOTS; do_sig = 0; }
    f32x4 acc = gemm_core(G, W, isf, j0, lane, wave);
    #pragma unroll
    for (int i = 0; i < 4; ++i){
        const unsigned short tj = tbl[lane * 4 + i];
        const int t = wave * 16 + (tj & 15);
        const int j = j0 + ((tj >> 8) & 15);
        float v = acc[i] + ldf(bias, j, isf);
        if (do_sig) v = sigmoidf_(v);
        out[(size_t)t * ostride + j] = v;
    }
}

// ---------------- sequential softmax/usage scan ----------------
__global__ void scan_k(const float* __restrict__ logits, const void* __restrict__ usage0,
                       const int* __restrict__ flags, float* __restrict__ wgt)
{
    const int isf = flags[0];
    const int lane = threadIdx.x; // 64 threads, 1 wave
    float u0 = ldf(usage0, lane,       isf);
    float u1 = ldf(usage0, lane + 64,  isf);
    float u2 = ldf(usage0, lane + 128, isf);
    float u3 = ldf(usage0, lane + 192, isf);
    for (int t = 0; t < TSTEPS; ++t){
        const float* lg = logits + t * SLOTS;
        float e0 = __expf(lg[lane]       - 0.1f * u0);
        float e1 = __expf(lg[lane + 64]  - 0.1f * u1);
        float e2 = __expf(lg[lane + 128] - 0.1f * u2);
        float e3 = __expf(lg[lane + 192] - 0.1f * u3);
        float s = (e0 + e1) + (e2 + e3);
        #pragma unroll
        for (int off = 1; off < 64; off <<= 1) s += __shfl_xor(s, off, 64);
        float inv = 1.0f / s;
        float w0 = e0 * inv, w1 = e1 * inv, w2 = e2 * inv, w3 = e3 * inv;
        u0 += w0; u1 += w1; u2 += w2; u3 += w3;
        float* wr = wgt + t * SLOTS;
        wr[lane] = w0; wr[lane + 64] = w1; wr[lane + 128] = w2; wr[lane + 192] = w3;
    }
}

// ---------------- memory recurrence: thread = slot, 8 d-columns per block; FP32 OUT ------
__global__ __launch_bounds__(256)
void mem_k(const void* __restrict__ mem0, const float* __restrict__ wgt,
           const float* __restrict__ erase, const float* __restrict__ addv,
           const int* __restrict__ flags, float* __restrict__ out)
{
    const int isf = flags[0];
    const int s = threadIdx.x;
    const int d0 = blockIdx.x * 8;
    float m[8];
    load8f(mem0, (size_t)s * DIM + d0, isf, m);
    for (int t = 0; t < TSTEPS; ++t){
        float w = 0.5f * wgt[t * SLOTS + s];
        float e8[8], a8[8];
        *(float4*)(e8)     = *(const float4*)(erase + (size_t)t * DIM + d0);
        *(float4*)(e8 + 4) = *(const float4*)(erase + (size_t)t * DIM + d0 + 4);
        *(float4*)(a8)     = *(const float4*)(addv  + (size_t)t * DIM + d0);
        *(float4*)(a8 + 4) = *(const float4*)(addv  + (size_t)t * DIM + d0 + 4);
        #pragma unroll
        for (int c = 0; c < 8; ++c){
            float f = w * e8[c];
            float tmp = fmaf(-f, m[c], m[c]);
            m[c] = fmaf(w, a8[c], tmp);
        }
    }
    float* op = out + (size_t)s * DIM + d0;
    *(float4*)(op)     = *(const float4*)(m);
    *(float4*)(op + 4) = *(const float4*)(m + 4);
}

extern "C" void kernel_launch(void* const* d_in, const int* in_sizes, int n_in,
                              void* d_out, int out_size, void* d_ws, size_t ws_size,
                              hipStream_t stream)
{
    const void* traces = d_in[0];
    const void* noise  = d_in[1];
    const void* mem0   = d_in[2];
    const void* usage0 = d_in[3];
    const void* W1 = d_in[4];  const void* b1 = d_in[5];
    const void* W2 = d_in[6];  const void* b2 = d_in[7];
    const void* Wl = d_in[8];  const void* bl = d_in[9];
    const void* vw = d_in[10]; const void* vb = d_in[11];
    const void* Wg = d_in[12]; const void* bg = d_in[13];
    const void* Wa = d_in[14]; const void* ba = d_in[15];
    const void* We = d_in[16]; const void* be = d_in[17];
    const void* Wad = d_in[18]; const void* bad_ = d_in[19];
    const int* idx = (const int*)d_in[20];

    char* ws = (char*)d_ws;
    int* FLAGS = (int*)ws;                               // 2 ints
    unsigned short* TBL = (unsigned short*)(ws + 16);    // 256 u16 = 512 B
    const size_t FB = (size_t)TSTEPS * DIM;              // 131072 floats per T x DIM buffer
    float* A0  = (float*)(ws + 1024);
    float* Hb  = A0  + FB;
    float* Xb  = Hb  + FB;
    float* LVb = Xb  + FB;
    float* Gb  = LVb + FB;
    float* ER  = Gb  + FB;
    float* AD  = ER  + FB;
    float* LG  = AD  + FB;                               // TSTEPS*SLOTS floats
    float* WG  = LG  + (size_t)TSTEPS * SLOTS;

    detect_k<<<1, 256, 0, stream>>>((const unsigned*)W1, idx, FLAGS);
    calib_k<<<1, 64, 0, stream>>>(TBL);
    prep<<<TSTEPS, 256, 0, stream>>>(traces, noise, idx, FLAGS, A0);
    gemm_stage<0><<<DIM / 16, 256, 0, stream>>>(A0,  W1, b1, nullptr, nullptr, nullptr, FLAGS, TBL, Hb);
    gemm_stage<1><<<DIM / 16, 256, 0, stream>>>(Hb,  W2, b2, nullptr, nullptr, nullptr, FLAGS, TBL, Xb);
    gemm_stage<2><<<DIM / 16, 256, 0, stream>>>(Xb,  Wl, bl, vw, vb, nullptr, FLAGS, TBL, LVb);
    gemm_stage<3><<<DIM / 16, 256, 0, stream>>>(LVb, Wg, bg, nullptr, nullptr, Xb, FLAGS, TBL, Gb);
    gemm_heads<<<2 * (DIM / 16) + SLOTS / 16, 256, 0, stream>>>(Gb, We, be, Wad, bad_, Wa, ba,
                                                                FLAGS, TBL, ER, AD, LG);
    scan_k<<<1, 64, 0, stream>>>(LG, usage0, FLAGS, WG);
    mem_k<<<DIM / 8, 256, 0, stream>>>(mem0, WG, ER, AD, FLAGS, (float*)d_out);
}

// Round 5
// 414.497 us; speedup vs baseline: 1.1039x; 1.1039x over previous
//
#include <hip/hip_runtime.h>
#include <math.h>

#define DIM 2048
#define SLOTS 256
#define TSTEPS 64
#define FB (TSTEPS * DIM)            // 131072 floats: one [64][2048] buffer

typedef unsigned short u16;
typedef __bf16 bf16x8 __attribute__((ext_vector_type(8)));
typedef float f32x4 __attribute__((ext_vector_type(4)));

union FragU { unsigned u[4]; bf16x8 v; };

__device__ __forceinline__ float bf2f(u16 h){
    union { unsigned u; float f; } v; v.u = ((unsigned)h) << 16; return v.f;
}
__device__ __forceinline__ u16 f2bf(float f){
    union { float f; unsigned u; } v; v.f = f;
    unsigned r = v.u + 0x7fffu + ((v.u >> 16) & 1u);
    return (u16)(r >> 16);
}
__device__ __forceinline__ float sigmoidf_(float x){ return 1.0f / (1.0f + __expf(-x)); }

// fast truncation-based f32 -> bf16 hi/lo split (~2^-16 rel error after 3-MFMA recombine)
__device__ __forceinline__ void split8t(const float* x, bf16x8& hi, bf16x8& lo){
    FragU H, L;
    #pragma unroll
    for (int p = 0; p < 4; ++p){
        union { float f; unsigned u; } u0, u1, l0, l1;
        u0.f = x[2*p]; u1.f = x[2*p+1];
        unsigned h0 = u0.u & 0xffff0000u, h1 = u1.u & 0xffff0000u;
        H.u[p] = (h0 >> 16) | h1;
        l0.f = u0.f - __uint_as_float(h0);
        l1.f = u1.f - __uint_as_float(h1);
        L.u[p] = (l0.u >> 16) | (l1.u & 0xffff0000u);
    }
    hi = H.v; lo = L.v;
}

__device__ __forceinline__ f32x4 mfma16(bf16x8 a, bf16x8 b, f32x4 c){
    return __builtin_amdgcn_mfma_f32_16x16x32_bf16(a, b, c, 0, 0, 0);
}

// ---------------- detection (idx int64?) + weight sanity flag ----------------
__global__ void detect_k(const unsigned* __restrict__ W1w, const int* __restrict__ idxw,
                         int* __restrict__ flags)
{
    __shared__ int nz_s;
    if (threadIdx.x == 0) nz_s = 0;
    __syncthreads();
    int nz = 0;
    if (threadIdx.x < 32 && idxw[2 * threadIdx.x + 1] != 0) nz = 1;
    atomicAdd(&nz_s, nz);
    __syncthreads();
    if (threadIdx.x == 0){
        flags[0] = 1;                 // f32 inputs (proven R1/R2/R4)
        flags[1] = (nz_s == 0) ? 1 : 0;   // idx is int64
    }
}

// ---------------- MFMA D-layout runtime calibration ----------------
__global__ void calib_k(u16* __restrict__ tbl)
{
    const int lane = threadIdx.x;
    const u16 oneb = 0x3F80;
    const u16 lb = f2bf((float)((lane & 15) + 1));
    FragU O, L;
    #pragma unroll
    for (int p = 0; p < 4; ++p){
        O.u[p] = ((unsigned)oneb) | (((unsigned)oneb) << 16);
        L.u[p] = ((unsigned)lb)   | (((unsigned)lb)   << 16);
    }
    f32x4 z = {0.f, 0.f, 0.f, 0.f};
    f32x4 dj = mfma16(O.v, L.v, z);
    f32x4 dt = mfma16(L.v, O.v, z);
    #pragma unroll
    for (int r = 0; r < 4; ++r){
        int jl = (int)(dj[r] * (1.0f/32.0f) + 0.5f) - 1;
        int tl = (int)(dt[r] * (1.0f/32.0f) + 0.5f) - 1;
        tbl[lane * 4 + r] = (u16)((tl & 15) | ((jl & 15) << 8));
    }
}

// ---------------- PREP: A0 = traces[idx] + 0.01*noise (f32) ----------------
__global__ __launch_bounds__(256)
void prep(const float* __restrict__ traces, const float* __restrict__ noise,
          const int* __restrict__ idxw, const int* __restrict__ flags,
          float* __restrict__ A0)
{
    const int t = blockIdx.x;
    long row = flags[1] ? (long)idxw[2 * t] : (long)idxw[t];
    const int k = threadIdx.x * 8;
    const float* tr = traces + (size_t)row * DIM + k;
    const float* nz = noise + (size_t)t * DIM + k;
    float4 a0 = *(const float4*)(tr), a1 = *(const float4*)(tr + 4);
    float4 b0 = *(const float4*)(nz), b1 = *(const float4*)(nz + 4);
    float4 r0, r1;
    r0.x = fmaf(0.01f, b0.x, a0.x); r0.y = fmaf(0.01f, b0.y, a0.y);
    r0.z = fmaf(0.01f, b0.z, a0.z); r0.w = fmaf(0.01f, b0.w, a0.w);
    r1.x = fmaf(0.01f, b1.x, a1.x); r1.y = fmaf(0.01f, b1.y, a1.y);
    r1.z = fmaf(0.01f, b1.z, a1.z); r1.w = fmaf(0.01f, b1.w, a1.w);
    float* o = A0 + (size_t)t * DIM + k;
    *(float4*)(o) = r0; *(float4*)(o + 4) = r1;
}

// ---------------- pipelined MFMA core ----------------
// AMODE 0: A = Asrc (plain)
// AMODE 1: A = relu(P0+P1+b)
// AMODE 2: A = P0+P1+b
// AMODE 3: A = sigmoid(P0+P1+b) * sigmoid(psr*vw + vb)
struct Pay {
    float4 w0, w1, a0, a1, c0, c1, b0, b1, x0, x1, y0, y1;
};

template<int AMODE>
__device__ __forceinline__ void pay_load(Pay& P, const float* __restrict__ ap,
                                         const float* __restrict__ cp, const float* __restrict__ bp,
                                         const float* __restrict__ xp, const float* __restrict__ yp,
                                         const float* __restrict__ wp, int it){
    const int o = it * 32;
    P.w0 = *(const float4*)(wp + o); P.w1 = *(const float4*)(wp + o + 4);
    P.a0 = *(const float4*)(ap + o); P.a1 = *(const float4*)(ap + o + 4);
    if (AMODE != 0){
        P.c0 = *(const float4*)(cp + o); P.c1 = *(const float4*)(cp + o + 4);
        P.b0 = *(const float4*)(bp + o); P.b1 = *(const float4*)(bp + o + 4);
    }
    if (AMODE == 3){
        P.x0 = *(const float4*)(xp + o); P.x1 = *(const float4*)(xp + o + 4);
        P.y0 = *(const float4*)(yp + o); P.y1 = *(const float4*)(yp + o + 4);
    }
}

template<int AMODE>
__device__ __forceinline__ void pay_consume(const Pay& P, float psr, f32x4& acc){
    float w8[8], a8[8], t8[8];
    *(float4*)(w8) = P.w0; *(float4*)(w8 + 4) = P.w1;
    *(float4*)(t8) = P.a0; *(float4*)(t8 + 4) = P.a1;
    if (AMODE == 0){
        #pragma unroll
        for (int i = 0; i < 8; ++i) a8[i] = t8[i];
    } else {
        float c8[8], b8[8];
        *(float4*)(c8) = P.c0; *(float4*)(c8 + 4) = P.c1;
        *(float4*)(b8) = P.b0; *(float4*)(b8 + 4) = P.b1;
        if (AMODE == 3){
            float x8[8], y8[8];
            *(float4*)(x8) = P.x0; *(float4*)(x8 + 4) = P.x1;
            *(float4*)(y8) = P.y0; *(float4*)(y8 + 4) = P.y1;
            #pragma unroll
            for (int i = 0; i < 8; ++i){
                float v = t8[i] + c8[i] + b8[i];
                float lig = sigmoidf_(v);
                float volt = sigmoidf_(fmaf(psr, x8[i], y8[i]));
                a8[i] = lig * volt;
            }
        } else {
            #pragma unroll
            for (int i = 0; i < 8; ++i){
                float v = t8[i] + c8[i] + b8[i];
                a8[i] = (AMODE == 1) ? fmaxf(v, 0.f) : v;
            }
        }
    }
    bf16x8 ah, al, wh, wl;
    split8t(a8, ah, al);
    split8t(w8, wh, wl);
    acc = mfma16(ah, wh, acc);
    acc = mfma16(al, wh, acc);
    acc = mfma16(ah, wl, acc);
}

template<int AMODE>
__device__ __forceinline__ f32x4 core(const float* __restrict__ ap, const float* __restrict__ cp,
                                      const float* __restrict__ bp, const float* __restrict__ xp,
                                      const float* __restrict__ yp, const float* __restrict__ wp,
                                      float psr){
    f32x4 acc = {0.f, 0.f, 0.f, 0.f};
    Pay p0, p1;
    pay_load<AMODE>(p0, ap, cp, bp, xp, yp, wp, 0);
    pay_load<AMODE>(p1, ap, cp, bp, xp, yp, wp, 1);
    #pragma unroll
    for (int it = 0; it < 32; ++it){
        Pay cur = (it & 1) ? p1 : p0;
        if (it + 2 < 32){
            if (it & 1) pay_load<AMODE>(p1, ap, cp, bp, xp, yp, wp, it + 2);
            else        pay_load<AMODE>(p0, ap, cp, bp, xp, yp, wp, it + 2);
        }
        pay_consume<AMODE>(cur, psr, acc);
    }
    return acc;
}

// ---------------- stage GEMM: grid = 128 j-tiles x 2 k-halves = 256 blocks ---------------
template<int AMODE>
__global__ __launch_bounds__(256)
void gemm2(const float* __restrict__ Asrc, const float* __restrict__ P0,
           const float* __restrict__ P1, const float* __restrict__ bias,
           const float* __restrict__ vw, const float* __restrict__ vb,
           const float* __restrict__ W, const u16* __restrict__ tbl,
           float* __restrict__ Pout)
{
    const int kh = blockIdx.x & 1;
    const int j0 = (blockIdx.x >> 1) * 16;
    const int lane = threadIdx.x & 63, wave = threadIdx.x >> 6;
    const int n = lane & 15, q = lane >> 4;
    const int trow = wave * 16 + n;
    const int kb = kh * (DIM / 2) + q * 8;
    const float* wp = W + (size_t)(j0 + n) * DIM + kb;
    const float *ap, *cp, *bp, *xp, *yp;
    if (AMODE == 0){
        ap = Asrc + (size_t)trow * DIM + kb; cp = ap; bp = ap; xp = ap; yp = ap;
    } else {
        ap = P0 + (size_t)trow * DIM + kb;
        cp = P1 + (size_t)trow * DIM + kb;
        bp = bias + kb;
        xp = (AMODE == 3) ? vw + kb : ap;
        yp = (AMODE == 3) ? vb + kb : ap;
    }
    float psr = (AMODE == 3) ? -cosf(0.37699111843077515f * (float)(trow + 1)) : 0.f;
    f32x4 acc = core<AMODE>(ap, cp, bp, xp, yp, wp, psr);
    float* outb = Pout + (size_t)kh * FB;
    #pragma unroll
    for (int r = 0; r < 4; ++r){
        u16 tj = tbl[lane * 4 + r];
        int t = wave * 16 + (tj & 15);
        int j = j0 + ((tj >> 8) & 15);
        outb[(size_t)t * DIM + j] = acc[r];
    }
}

// ---------------- heads GEMM: 272 j-tiles x 2 k-halves = 544 blocks ----------------------
__global__ __launch_bounds__(256)
void gemm_heads2(const float* __restrict__ GT,
                 const float* __restrict__ We, const float* __restrict__ Wad,
                 const float* __restrict__ Wa, const u16* __restrict__ tbl,
                 float* __restrict__ PE, float* __restrict__ PA, float* __restrict__ PL)
{
    const int kh = blockIdx.x & 1;
    const int jt = blockIdx.x >> 1;
    const float* W; float* out; int j0, NJ;
    if (jt < 128)      { W = We;  out = PE; j0 = jt * 16;         NJ = DIM; }
    else if (jt < 256) { W = Wad; out = PA; j0 = (jt - 128) * 16; NJ = DIM; }
    else               { W = Wa;  out = PL; j0 = (jt - 256) * 16; NJ = SLOTS; }
    const int lane = threadIdx.x & 63, wave = threadIdx.x >> 6;
    const int n = lane & 15, q = lane >> 4;
    const int trow = wave * 16 + n;
    const int kb = kh * (DIM / 2) + q * 8;
    const float* wp = W + (size_t)(j0 + n) * DIM + kb;
    const float* ap = GT + (size_t)trow * DIM + kb;
    f32x4 acc = core<0>(ap, ap, ap, ap, ap, wp, 0.f);
    float* outb = out + (size_t)kh * 64 * NJ;
    #pragma unroll
    for (int r = 0; r < 4; ++r){
        u16 tj = tbl[lane * 4 + r];
        int t = wave * 16 + (tj & 15);
        int j = j0 + ((tj >> 8) & 15);
        outb[(size_t)t * NJ + j] = acc[r];
    }
}

// ---------------- gated = (P2S+b2) * sigmoid(P4S+bg) ----------------
__global__ __launch_bounds__(256)
void gated_k(const float* __restrict__ P2, const float* __restrict__ P4,
             const float* __restrict__ b2, const float* __restrict__ bg,
             float* __restrict__ GT)
{
    const size_t i0 = ((size_t)blockIdx.x * 256 + threadIdx.x) * 8;
    const int k = (int)(i0 & (DIM - 1));
    float p2a[8], p2b[8], p4a[8], p4b[8], bb2[8], bbg[8];
    *(float4*)(p2a)     = *(const float4*)(P2 + i0);
    *(float4*)(p2a + 4) = *(const float4*)(P2 + i0 + 4);
    *(float4*)(p2b)     = *(const float4*)(P2 + FB + i0);
    *(float4*)(p2b + 4) = *(const float4*)(P2 + FB + i0 + 4);
    *(float4*)(p4a)     = *(const float4*)(P4 + i0);
    *(float4*)(p4a + 4) = *(const float4*)(P4 + i0 + 4);
    *(float4*)(p4b)     = *(const float4*)(P4 + FB + i0);
    *(float4*)(p4b + 4) = *(const float4*)(P4 + FB + i0 + 4);
    *(float4*)(bb2)     = *(const float4*)(b2 + k);
    *(float4*)(bb2 + 4) = *(const float4*)(b2 + k + 4);
    *(float4*)(bbg)     = *(const float4*)(bg + k);
    *(float4*)(bbg + 4) = *(const float4*)(bg + k + 4);
    float r[8];
    #pragma unroll
    for (int c = 0; c < 8; ++c){
        float x = p2a[c] + p2b[c] + bb2[c];
        float g = sigmoidf_(p4a[c] + p4b[c] + bbg[c]);
        r[c] = x * g;
    }
    *(float4*)(GT + i0)     = *(const float4*)(r);
    *(float4*)(GT + i0 + 4) = *(const float4*)(r + 4);
}

// ---------------- sequential softmax/usage scan (logits = PLS + ba) ----------------
__global__ void scan_k(const float* __restrict__ PL, const float* __restrict__ ba,
                       const float* __restrict__ usage0, float* __restrict__ wgt)
{
    const int lane = threadIdx.x;   // 1 wave, 4 slots/lane
    float u[4], bav[4];
    #pragma unroll
    for (int c = 0; c < 4; ++c){
        u[c] = usage0[lane + 64 * c];
        bav[c] = ba[lane + 64 * c];
    }
    const float* L0 = PL;
    const float* L1 = PL + TSTEPS * SLOTS;
    for (int t = 0; t < TSTEPS; ++t){
        float e[4];
        #pragma unroll
        for (int c = 0; c < 4; ++c){
            int s = lane + 64 * c;
            float lg = L0[t * SLOTS + s] + L1[t * SLOTS + s] + bav[c];
            e[c] = __expf(lg - 0.1f * u[c]);
        }
        float s = (e[0] + e[1]) + (e[2] + e[3]);
        #pragma unroll
        for (int off = 1; off < 64; off <<= 1) s += __shfl_xor(s, off, 64);
        float inv = 1.0f / s;
        float* wr = wgt + t * SLOTS;
        #pragma unroll
        for (int c = 0; c < 4; ++c){
            float w = e[c] * inv;
            u[c] += w;
            wr[lane + 64 * c] = w;
        }
    }
}

// ---------------- memory recurrence (erase/add reconstructed from partials) --------------
__global__ __launch_bounds__(256)
void mem_k(const float* __restrict__ mem0, const float* __restrict__ wgt,
           const float* __restrict__ PE, const float* __restrict__ PA,
           const float* __restrict__ be, const float* __restrict__ bad_,
           float* __restrict__ out)
{
    const int s = threadIdx.x;
    const int d0 = blockIdx.x * 8;
    float m[8], beb[8], bab[8];
    *(float4*)(m)       = *(const float4*)(mem0 + (size_t)s * DIM + d0);
    *(float4*)(m + 4)   = *(const float4*)(mem0 + (size_t)s * DIM + d0 + 4);
    *(float4*)(beb)     = *(const float4*)(be + d0);
    *(float4*)(beb + 4) = *(const float4*)(be + d0 + 4);
    *(float4*)(bab)     = *(const float4*)(bad_ + d0);
    *(float4*)(bab + 4) = *(const float4*)(bad_ + d0 + 4);
    for (int t = 0; t < TSTEPS; ++t){
        const size_t ro = (size_t)t * DIM + d0;
        float e0[8], e1[8], a0[8], a1[8];
        *(float4*)(e0)     = *(const float4*)(PE + ro);
        *(float4*)(e0 + 4) = *(const float4*)(PE + ro + 4);
        *(float4*)(e1)     = *(const float4*)(PE + FB + ro);
        *(float4*)(e1 + 4) = *(const float4*)(PE + FB + ro + 4);
        *(float4*)(a0)     = *(const float4*)(PA + ro);
        *(float4*)(a0 + 4) = *(const float4*)(PA + ro + 4);
        *(float4*)(a1)     = *(const float4*)(PA + FB + ro);
        *(float4*)(a1 + 4) = *(const float4*)(PA + FB + ro + 4);
        float w = 0.5f * wgt[t * SLOTS + s];
        #pragma unroll
        for (int c = 0; c < 8; ++c){
            float er = sigmoidf_(e0[c] + e1[c] + beb[c]);
            float ad = a0[c] + a1[c] + bab[c];
            float f = w * er;
            float tmp = fmaf(-f, m[c], m[c]);
            m[c] = fmaf(w, ad, tmp);
        }
    }
    float* op = out + (size_t)s * DIM + d0;
    *(float4*)(op)     = *(const float4*)(m);
    *(float4*)(op + 4) = *(const float4*)(m + 4);
}

extern "C" void kernel_launch(void* const* d_in, const int* in_sizes, int n_in,
                              void* d_out, int out_size, void* d_ws, size_t ws_size,
                              hipStream_t stream)
{
    const float* traces = (const float*)d_in[0];
    const float* noise  = (const float*)d_in[1];
    const float* mem0   = (const float*)d_in[2];
    const float* usage0 = (const float*)d_in[3];
    const float* W1 = (const float*)d_in[4];  const float* b1 = (const float*)d_in[5];
    const float* W2 = (const float*)d_in[6];  const float* b2 = (const float*)d_in[7];
    const float* Wl = (const float*)d_in[8];  const float* bl = (const float*)d_in[9];
    const float* vw = (const float*)d_in[10]; const float* vb = (const float*)d_in[11];
    const float* Wg = (const float*)d_in[12]; const float* bg = (const float*)d_in[13];
    const float* Wa = (const float*)d_in[14]; const float* ba = (const float*)d_in[15];
    const float* We = (const float*)d_in[16]; const float* be = (const float*)d_in[17];
    const float* Wad = (const float*)d_in[18]; const float* bad_ = (const float*)d_in[19];
    const int* idx = (const int*)d_in[20];

    char* ws = (char*)d_ws;
    int* FLAGS = (int*)ws;
    u16* TBL = (u16*)(ws + 16);
    float* pool = (float*)(ws + 1024);
    float* A0v = pool;                        // [64][2048]
    float* P1v = pool + FB;                   // [2][64][2048]
    float* P2v = pool + FB + 2 * FB;          // [2][64][2048]
    float* P3v = pool + FB + 4 * FB;          // [2][64][2048]
    float* P4v = P1v;                         // alias: P1 dead after g2
    float* GTv = pool + FB + 6 * FB;          // [64][2048]
    float* PEv = P3v;                         // alias: P3 dead after g4
    float* PAv = P2v;                         // alias: P2 dead after gated_k
    float* PLv = pool + 8 * FB;               // [2][64][256]
    float* WGv = PLv + 2 * TSTEPS * SLOTS;    // [64][256]

    detect_k<<<1, 256, 0, stream>>>((const unsigned*)W1, idx, FLAGS);
    calib_k<<<1, 64, 0, stream>>>(TBL);
    prep<<<TSTEPS, 256, 0, stream>>>(traces, noise, idx, FLAGS, A0v);
    gemm2<0><<<256, 256, 0, stream>>>(A0v, A0v, A0v, A0v, A0v, A0v, W1, TBL, P1v);
    gemm2<1><<<256, 256, 0, stream>>>(A0v, P1v, P1v + FB, b1, A0v, A0v, W2, TBL, P2v);
    gemm2<2><<<256, 256, 0, stream>>>(A0v, P2v, P2v + FB, b2, A0v, A0v, Wl, TBL, P3v);
    gemm2<3><<<256, 256, 0, stream>>>(A0v, P3v, P3v + FB, bl, vw, vb, Wg, TBL, P4v);
    gated_k<<<64, 256, 0, stream>>>(P2v, P4v, b2, bg, GTv);
    gemm_heads2<<<544, 256, 0, stream>>>(GTv, We, Wad, Wa, TBL, PEv, PAv, PLv);
    scan_k<<<1, 64, 0, stream>>>(PLv, ba, usage0, WGv);
    mem_k<<<DIM / 8, 256, 0, stream>>>(mem0, WGv, PEv, PAv, be, bad_, (float*)d_out);
}

// Round 6
// 398.647 us; speedup vs baseline: 1.1478x; 1.0398x over previous
//
#include <hip/hip_runtime.h>
#include <math.h>

#define DIM 2048
#define SLOTS 256
#define TSTEPS 64
#define FB (TSTEPS * DIM)

typedef unsigned short u16;
typedef __bf16 bf16x8 __attribute__((ext_vector_type(8)));
typedef float f32x4 __attribute__((ext_vector_type(4)));

union FragU { unsigned u[4]; bf16x8 v; };

__device__ __forceinline__ float bf2f(u16 h){
    union { unsigned u; float f; } v; v.u = ((unsigned)h) << 16; return v.f;
}
__device__ __forceinline__ u16 f2bf(float f){
    union { float f; unsigned u; } v; v.f = f;
    unsigned r = v.u + 0x7fffu + ((v.u >> 16) & 1u);
    return (u16)(r >> 16);
}
__device__ __forceinline__ float sigmoidf_(float x){ return 1.0f / (1.0f + __expf(-x)); }

// truncation-based f32 -> bf16 hi/lo split
__device__ __forceinline__ void split8t(const float* x, bf16x8& hi, bf16x8& lo){
    FragU H, L;
    #pragma unroll
    for (int p = 0; p < 4; ++p){
        union { float f; unsigned u; } u0, u1, l0, l1;
        u0.f = x[2*p]; u1.f = x[2*p+1];
        unsigned h0 = u0.u & 0xffff0000u, h1 = u1.u & 0xffff0000u;
        H.u[p] = (h0 >> 16) | h1;
        l0.f = u0.f - __uint_as_float(h0);
        l1.f = u1.f - __uint_as_float(h1);
        L.u[p] = (l0.u >> 16) | (l1.u & 0xffff0000u);
    }
    hi = H.v; lo = L.v;
}

__device__ __forceinline__ f32x4 mfma16(bf16x8 a, bf16x8 b, f32x4 c){
    return __builtin_amdgcn_mfma_f32_16x16x32_bf16(a, b, c, 0, 0, 0);
}

// ---------------- detection: idx int64? ----------------
__global__ void detect_k(const int* __restrict__ idxw, int* __restrict__ flags)
{
    __shared__ int nz_s;
    if (threadIdx.x == 0) nz_s = 0;
    __syncthreads();
    int nz = 0;
    if (threadIdx.x < 32 && idxw[2 * threadIdx.x + 1] != 0) nz = 1;
    atomicAdd(&nz_s, nz);
    __syncthreads();
    if (threadIdx.x == 0) flags[1] = (nz_s == 0) ? 1 : 0;
}

// ---------------- MFMA D-layout runtime calibration ----------------
__global__ void calib_k(u16* __restrict__ tbl)
{
    const int lane = threadIdx.x;
    const u16 oneb = 0x3F80;
    const u16 lb = f2bf((float)((lane & 15) + 1));
    FragU O, L;
    #pragma unroll
    for (int p = 0; p < 4; ++p){
        O.u[p] = ((unsigned)oneb) | (((unsigned)oneb) << 16);
        L.u[p] = ((unsigned)lb)   | (((unsigned)lb)   << 16);
    }
    f32x4 z = {0.f, 0.f, 0.f, 0.f};
    f32x4 dj = mfma16(O.v, L.v, z);
    f32x4 dt = mfma16(L.v, O.v, z);
    #pragma unroll
    for (int r = 0; r < 4; ++r){
        int jl = (int)(dj[r] * (1.0f/32.0f) + 0.5f) - 1;
        int tl = (int)(dt[r] * (1.0f/32.0f) + 0.5f) - 1;
        tbl[lane * 4 + r] = (u16)((tl & 15) | ((jl & 15) << 8));
    }
}

// ---------------- PREP: A0 = traces[idx] + 0.01*noise ----------------
__global__ __launch_bounds__(256)
void prep(const float* __restrict__ traces, const float* __restrict__ noise,
          const int* __restrict__ idxw, const int* __restrict__ flags,
          float* __restrict__ A0)
{
    const int t = blockIdx.x;
    long row = flags[1] ? (long)idxw[2 * t] : (long)idxw[t];
    const int k = threadIdx.x * 8;
    const float* tr = traces + (size_t)row * DIM + k;
    const float* nz = noise + (size_t)t * DIM + k;
    float4 a0 = *(const float4*)(tr), a1 = *(const float4*)(tr + 4);
    float4 b0 = *(const float4*)(nz), b1 = *(const float4*)(nz + 4);
    float4 r0, r1;
    r0.x = fmaf(0.01f, b0.x, a0.x); r0.y = fmaf(0.01f, b0.y, a0.y);
    r0.z = fmaf(0.01f, b0.z, a0.z); r0.w = fmaf(0.01f, b0.w, a0.w);
    r1.x = fmaf(0.01f, b1.x, a1.x); r1.y = fmaf(0.01f, b1.y, a1.y);
    r1.z = fmaf(0.01f, b1.z, a1.z); r1.w = fmaf(0.01f, b1.w, a1.w);
    float* o = A0 + (size_t)t * DIM + k;
    *(float4*)(o) = r0; *(float4*)(o + 4) = r1;
}

// ---------------- depth-2 pipelined K-loop pieces ----------------
struct KPipe { float4 a0, a1, w0, w1; };

__device__ __forceinline__ void kload(KPipe& s, const float* __restrict__ ap,
                                      const float* __restrict__ wp, int it){
    const int o = it * 32;
    s.a0 = *(const float4*)(ap + o); s.a1 = *(const float4*)(ap + o + 4);
    s.w0 = *(const float4*)(wp + o); s.w1 = *(const float4*)(wp + o + 4);
}
__device__ __forceinline__ void kcons(const KPipe& s, f32x4& acc){
    float a8[8], w8[8];
    *(float4*)(a8) = s.a0; *(float4*)(a8 + 4) = s.a1;
    *(float4*)(w8) = s.w0; *(float4*)(w8 + 4) = s.w1;
    bf16x8 ah, al, wh, wl;
    split8t(a8, ah, al);
    split8t(w8, wh, wl);
    acc = mfma16(ah, wh, acc);
    acc = mfma16(al, wh, acc);
    acc = mfma16(ah, wl, acc);
}

// wave-level core: 16 k-iterations (512 cols), depth-2 modulo-3 pipeline
__device__ __forceinline__ f32x4 kcore16(const float* __restrict__ ap, const float* __restrict__ wp){
    f32x4 acc = {0.f, 0.f, 0.f, 0.f};
    KPipe s0, s1, s2;
    kload(s0, ap, wp, 0);
    kload(s1, ap, wp, 1);
    #pragma unroll
    for (int it = 0; it < 16; ++it){
        // prefetch it+2 into the slot freed at it-1, BEFORE consuming current
        if (it + 2 < 16){
            if ((it + 2) % 3 == 0) kload(s0, ap, wp, it + 2);
            else if ((it + 2) % 3 == 1) kload(s1, ap, wp, it + 2);
            else kload(s2, ap, wp, it + 2);
        }
        if (it % 3 == 0) kcons(s0, acc);
        else if (it % 3 == 1) kcons(s1, acc);
        else kcons(s2, acc);
    }
    return acc;
}

// ---------------- block GEMM: 1024 thr = 4 mq x 4 kq waves; LDS reduce; fused epilogue ----
// MODE 0: relu(v+b)        MODE 1: v+b        MODE 2: sigmoid(v+b)*volt(t,j)
// MODE 3: X[t][j]*sigmoid(v+b)
template<int MODE>
__global__ __launch_bounds__(1024, 4)
void gemm3(const float* __restrict__ A, const float* __restrict__ W,
           const float* __restrict__ bias, const float* __restrict__ vw,
           const float* __restrict__ vb, const float* __restrict__ Xbuf,
           const u16* __restrict__ tbl, float* __restrict__ Pout)
{
    __shared__ float red[4][64][17];
    const int tid = threadIdx.x;
    const int lane = tid & 63, wave = tid >> 6;
    const int mq = wave & 3, kq = wave >> 2;
    const int n = lane & 15, q = lane >> 4;
    const int j0 = blockIdx.x * 16;
    const float* ap = A + (size_t)(mq * 16 + n) * DIM + kq * 512 + q * 8;
    const float* wp = W + (size_t)(j0 + n) * DIM + kq * 512 + q * 8;
    f32x4 acc = kcore16(ap, wp);
    #pragma unroll
    for (int r = 0; r < 4; ++r){
        u16 tj = tbl[lane * 4 + r];
        red[kq][mq * 16 + (tj & 15)][(tj >> 8) & 15] = acc[r];
    }
    __syncthreads();
    const int t = tid >> 4, jl = tid & 15;
    const int j = j0 + jl;
    float v = (red[0][t][jl] + red[1][t][jl]) + (red[2][t][jl] + red[3][t][jl]);
    v += bias[j];
    if (MODE == 0){
        v = fmaxf(v, 0.f);
    } else if (MODE == 2){
        float lig = sigmoidf_(v);
        float ps = -cosf(0.37699111843077515f * (float)(t + 1));
        float volt = sigmoidf_(fmaf(ps, vw[j], vb[j]));
        v = lig * volt;
    } else if (MODE == 3){
        v = Xbuf[(size_t)t * DIM + j] * sigmoidf_(v);
    }
    Pout[(size_t)t * DIM + j] = v;
}

// ---------------- heads: 272 blocks (128 We -> ER, 128 Wad -> AD, 16 Wa -> LG) -----------
__global__ __launch_bounds__(1024, 4)
void gemm3h(const float* __restrict__ G,
            const float* __restrict__ We, const float* __restrict__ Wad,
            const float* __restrict__ Wa, const float* __restrict__ be,
            const float* __restrict__ bad_, const float* __restrict__ ba,
            const u16* __restrict__ tbl,
            float* __restrict__ ER, float* __restrict__ AD, float* __restrict__ LG)
{
    __shared__ float red[4][64][17];
    const int jt = blockIdx.x;
    const float* W; const float* bias; float* out; int j0, NJ, op;
    if (jt < 128)      { W = We;  bias = be;   out = ER; j0 = jt * 16;         NJ = DIM;   op = 1; }
    else if (jt < 256) { W = Wad; bias = bad_; out = AD; j0 = (jt - 128) * 16; NJ = DIM;   op = 0; }
    else               { W = Wa;  bias = ba;   out = LG; j0 = (jt - 256) * 16; NJ = SLOTS; op = 0; }
    const int tid = threadIdx.x;
    const int lane = tid & 63, wave = tid >> 6;
    const int mq = wave & 3, kq = wave >> 2;
    const int n = lane & 15, q = lane >> 4;
    const float* ap = G + (size_t)(mq * 16 + n) * DIM + kq * 512 + q * 8;
    const float* wp = W + (size_t)(j0 + n) * DIM + kq * 512 + q * 8;
    f32x4 acc = kcore16(ap, wp);
    #pragma unroll
    for (int r = 0; r < 4; ++r){
        u16 tj = tbl[lane * 4 + r];
        red[kq][mq * 16 + (tj & 15)][(tj >> 8) & 15] = acc[r];
    }
    __syncthreads();
    const int t = tid >> 4, jl = tid & 15;
    const int j = j0 + jl;
    float v = (red[0][t][jl] + red[1][t][jl]) + (red[2][t][jl] + red[3][t][jl]);
    v += bias[j];
    if (op == 1) v = sigmoidf_(v);
    out[(size_t)t * NJ + j] = v;
}

// ---------------- sequential softmax/usage scan ----------------
__global__ void scan_k(const float* __restrict__ LG, const float* __restrict__ usage0,
                       float* __restrict__ wgt)
{
    const int lane = threadIdx.x;   // 1 wave, 4 slots/lane
    float u[4];
    #pragma unroll
    for (int c = 0; c < 4; ++c) u[c] = usage0[lane + 64 * c];
    for (int t = 0; t < TSTEPS; ++t){
        float e[4];
        #pragma unroll
        for (int c = 0; c < 4; ++c){
            int s = lane + 64 * c;
            e[c] = __expf(LG[t * SLOTS + s] - 0.1f * u[c]);
        }
        float s = (e[0] + e[1]) + (e[2] + e[3]);
        #pragma unroll
        for (int off = 1; off < 64; off <<= 1) s += __shfl_xor(s, off, 64);
        float inv = 1.0f / s;
        float* wr = wgt + t * SLOTS;
        #pragma unroll
        for (int c = 0; c < 4; ++c){
            float w = e[c] * inv;
            u[c] += w;
            wr[lane + 64 * c] = w;
        }
    }
}

// ---------------- memory recurrence ----------------
__global__ __launch_bounds__(256)
void mem_k(const float* __restrict__ mem0, const float* __restrict__ wgt,
           const float* __restrict__ ER, const float* __restrict__ AD,
           float* __restrict__ out)
{
    const int s = threadIdx.x;
    const int d0 = blockIdx.x * 8;
    float m[8];
    *(float4*)(m)     = *(const float4*)(mem0 + (size_t)s * DIM + d0);
    *(float4*)(m + 4) = *(const float4*)(mem0 + (size_t)s * DIM + d0 + 4);
    for (int t = 0; t < TSTEPS; ++t){
        const size_t ro = (size_t)t * DIM + d0;
        float e8[8], a8[8];
        *(float4*)(e8)     = *(const float4*)(ER + ro);
        *(float4*)(e8 + 4) = *(const float4*)(ER + ro + 4);
        *(float4*)(a8)     = *(const float4*)(AD + ro);
        *(float4*)(a8 + 4) = *(const float4*)(AD + ro + 4);
        float w = 0.5f * wgt[t * SLOTS + s];
        #pragma unroll
        for (int c = 0; c < 8; ++c){
            float f = w * e8[c];
            float tmp = fmaf(-f, m[c], m[c]);
            m[c] = fmaf(w, a8[c], tmp);
        }
    }
    float* op = out + (size_t)s * DIM + d0;
    *(float4*)(op)     = *(const float4*)(m);
    *(float4*)(op + 4) = *(const float4*)(m + 4);
}

extern "C" void kernel_launch(void* const* d_in, const int* in_sizes, int n_in,
                              void* d_out, int out_size, void* d_ws, size_t ws_size,
                              hipStream_t stream)
{
    const float* traces = (const float*)d_in[0];
    const float* noise  = (const float*)d_in[1];
    const float* mem0   = (const float*)d_in[2];
    const float* usage0 = (const float*)d_in[3];
    const float* W1 = (const float*)d_in[4];  const float* b1 = (const float*)d_in[5];
    const float* W2 = (const float*)d_in[6];  const float* b2 = (const float*)d_in[7];
    const float* Wl = (const float*)d_in[8];  const float* bl = (const float*)d_in[9];
    const float* vw = (const float*)d_in[10]; const float* vb = (const float*)d_in[11];
    const float* Wg = (const float*)d_in[12]; const float* bg = (const float*)d_in[13];
    const float* Wa = (const float*)d_in[14]; const float* ba = (const float*)d_in[15];
    const float* We = (const float*)d_in[16]; const float* be = (const float*)d_in[17];
    const float* Wad = (const float*)d_in[18]; const float* bad_ = (const float*)d_in[19];
    const int* idx = (const int*)d_in[20];

    char* ws = (char*)d_ws;
    int* FLAGS = (int*)ws;
    u16* TBL = (u16*)(ws + 16);
    float* pool = (float*)(ws + 1024);
    float* A0v = pool;                 // [64][2048]
    float* Hv  = pool + 1 * FB;
    float* Xv  = pool + 2 * FB;
    float* LVv = pool + 3 * FB;
    float* Gv  = pool + 4 * FB;
    float* ERv = pool + 5 * FB;
    float* ADv = pool + 6 * FB;
    float* LGv = pool + 7 * FB;                    // [64][256]
    float* WGv = LGv + (size_t)TSTEPS * SLOTS;     // [64][256]

    detect_k<<<1, 256, 0, stream>>>(idx, FLAGS);
    calib_k<<<1, 64, 0, stream>>>(TBL);
    prep<<<TSTEPS, 256, 0, stream>>>(traces, noise, idx, FLAGS, A0v);
    gemm3<0><<<128, 1024, 0, stream>>>(A0v, W1, b1, A0v, A0v, A0v, TBL, Hv);
    gemm3<1><<<128, 1024, 0, stream>>>(Hv,  W2, b2, A0v, A0v, A0v, TBL, Xv);
    gemm3<2><<<128, 1024, 0, stream>>>(Xv,  Wl, bl, vw, vb, A0v, TBL, LVv);
    gemm3<3><<<128, 1024, 0, stream>>>(LVv, Wg, bg, A0v, A0v, Xv, TBL, Gv);
    gemm3h<<<272, 1024, 0, stream>>>(Gv, We, Wad, Wa, be, bad_, ba, TBL, ERv, ADv, LGv);
    scan_k<<<1, 64, 0, stream>>>(LGv, usage0, WGv);
    mem_k<<<DIM / 8, 256, 0, stream>>>(mem0, WGv, ERv, ADv, (float*)d_out);
}

// Round 7
// 316.835 us; speedup vs baseline: 1.4442x; 1.2582x over previous
//
#include <hip/hip_runtime.h>
#include <math.h>

#define DIM 2048
#define SLOTS 256
#define TSTEPS 64
#define FB (TSTEPS * DIM)          // 131072 floats
#define KQ 4                       // K-split factor: K/block = 512
#define BK 64                      // k-chunk (cols) staged per iteration

typedef unsigned short u16;
typedef __bf16 bf16x8 __attribute__((ext_vector_type(8)));
typedef float f32x4 __attribute__((ext_vector_type(4)));

union FragU { unsigned u[4]; bf16x8 v; };

__device__ __forceinline__ float bf2f(u16 h){
    union { unsigned u; float f; } v; v.u = ((unsigned)h) << 16; return v.f;
}
__device__ __forceinline__ u16 f2bf(float f){
    union { float f; unsigned u; } v; v.f = f;
    unsigned r = v.u + 0x7fffu + ((v.u >> 16) & 1u);
    return (u16)(r >> 16);
}
__device__ __forceinline__ float sigmoidf_(float x){ return 1.0f / (1.0f + __expf(-x)); }

__device__ __forceinline__ void split8t(const float* x, bf16x8& hi, bf16x8& lo){
    FragU H, L;
    #pragma unroll
    for (int p = 0; p < 4; ++p){
        union { float f; unsigned u; } u0, u1, l0, l1;
        u0.f = x[2*p]; u1.f = x[2*p+1];
        unsigned h0 = u0.u & 0xffff0000u, h1 = u1.u & 0xffff0000u;
        H.u[p] = (h0 >> 16) | h1;
        l0.f = u0.f - __uint_as_float(h0);
        l1.f = u1.f - __uint_as_float(h1);
        L.u[p] = (l0.u >> 16) | (l1.u & 0xffff0000u);
    }
    hi = H.v; lo = L.v;
}

__device__ __forceinline__ f32x4 mfma16(bf16x8 a, bf16x8 b, f32x4 c){
    return __builtin_amdgcn_mfma_f32_16x16x32_bf16(a, b, c, 0, 0, 0);
}

// async global->LDS, 16B per lane; lds base must be wave-uniform, lane i lands at +i*16
__device__ __forceinline__ void gl_lds16(const float* gp, float* lp){
    __builtin_amdgcn_global_load_lds(
        (const __attribute__((address_space(1))) unsigned int*)gp,
        (__attribute__((address_space(3))) unsigned int*)lp, 16, 0, 0);
}

// ---------------- detection: idx int64? ----------------
__global__ void detect_k(const int* __restrict__ idxw, int* __restrict__ flags)
{
    __shared__ int nz_s;
    if (threadIdx.x == 0) nz_s = 0;
    __syncthreads();
    int nz = 0;
    if (threadIdx.x < 32 && idxw[2 * threadIdx.x + 1] != 0) nz = 1;
    atomicAdd(&nz_s, nz);
    __syncthreads();
    if (threadIdx.x == 0) flags[1] = (nz_s == 0) ? 1 : 0;
}

// ---------------- MFMA D-layout runtime calibration ----------------
__global__ void calib_k(u16* __restrict__ tbl)
{
    const int lane = threadIdx.x;
    const u16 oneb = 0x3F80;
    const u16 lb = f2bf((float)((lane & 15) + 1));
    FragU O, L;
    #pragma unroll
    for (int p = 0; p < 4; ++p){
        O.u[p] = ((unsigned)oneb) | (((unsigned)oneb) << 16);
        L.u[p] = ((unsigned)lb)   | (((unsigned)lb)   << 16);
    }
    f32x4 z = {0.f, 0.f, 0.f, 0.f};
    f32x4 dj = mfma16(O.v, L.v, z);
    f32x4 dt = mfma16(L.v, O.v, z);
    #pragma unroll
    for (int r = 0; r < 4; ++r){
        int jl = (int)(dj[r] * (1.0f/32.0f) + 0.5f) - 1;
        int tl = (int)(dt[r] * (1.0f/32.0f) + 0.5f) - 1;
        tbl[lane * 4 + r] = (u16)((tl & 15) | ((jl & 15) << 8));
    }
}

// ---------------- PREP: A0 = traces[idx] + 0.01*noise ----------------
__global__ __launch_bounds__(256)
void prep(const float* __restrict__ traces, const float* __restrict__ noise,
          const int* __restrict__ idxw, const int* __restrict__ flags,
          float* __restrict__ A0)
{
    const int t = blockIdx.x;
    long row = flags[1] ? (long)idxw[2 * t] : (long)idxw[t];
    const int k = threadIdx.x * 8;
    const float* tr = traces + (size_t)row * DIM + k;
    const float* nz = noise + (size_t)t * DIM + k;
    float4 a0 = *(const float4*)(tr), a1 = *(const float4*)(tr + 4);
    float4 b0 = *(const float4*)(nz), b1 = *(const float4*)(nz + 4);
    float4 r0, r1;
    r0.x = fmaf(0.01f, b0.x, a0.x); r0.y = fmaf(0.01f, b0.y, a0.y);
    r0.z = fmaf(0.01f, b0.z, a0.z); r0.w = fmaf(0.01f, b0.w, a0.w);
    r1.x = fmaf(0.01f, b1.x, a1.x); r1.y = fmaf(0.01f, b1.y, a1.y);
    r1.z = fmaf(0.01f, b1.z, a1.z); r1.w = fmaf(0.01f, b1.w, a1.w);
    float* o = A0 + (size_t)t * DIM + k;
    *(float4*)(o) = r0; *(float4*)(o + 4) = r1;
}

// ---------------- m97-lite GEMM body (shared by stage + heads kernels) -------------------
// Block: 256 thr / 4 waves (wave = m-quarter). Tile: 16 j-cols, K = DIM/KQ = 512,
// staged in 8 chunks of BK=64 via global_load_lds into XOR-swizzled LDS.
// At[64][64] f32, Wt[16][64] f32; slot for (row, colgrp cg) is (cg ^ (row&15)).
__device__ __forceinline__ void gemm_body(const float* __restrict__ A,
                                          const float* __restrict__ Wrow0,
                                          int kq, float* At, float* Wt,
                                          const u16* __restrict__ tbl,
                                          f32x4& acc, int* tout, int* jout)
{
    const int tid = threadIdx.x;
    const int lane = tid & 63, w = tid >> 6;
    const int s = lane & 15, rsub = lane >> 4;
    const int n4 = lane & 15;
    const int kbase = kq * (DIM / KQ);

    acc = (f32x4){0.f, 0.f, 0.f, 0.f};

    for (int c = 0; c < (DIM / KQ) / BK; ++c){
        const int kc = kbase + c * BK;
        // ---- stage: A rows w*16..w*16+15 (4 instrs), W rows w*4..w*4+3 (1 instr) ----
        #pragma unroll
        for (int i = 0; i < 4; ++i){
            const int rowL = w * 16 + i * 4 + rsub;
            const float* gp = A + (size_t)rowL * DIM + kc + ((s ^ (rowL & 15)) << 2);
            gl_lds16(gp, At + (w * 16 + i * 4) * BK);
        }
        {
            const int rowL = w * 4 + rsub;
            const float* gp = Wrow0 + (size_t)rowL * DIM + kc + ((s ^ (rowL & 15)) << 2);
            gl_lds16(gp, Wt + (w * 4) * BK);
        }
        __syncthreads();   // compiler emits vmcnt(0) drain before barrier
        // ---- compute: 2 k-steps of 32 ----
        #pragma unroll
        for (int ks = 0; ks < 2; ++ks){
            const int cg0 = ks * 8 + (lane >> 4) * 2;
            const int rA = w * 16 + n4;
            float a8[8], w8[8];
            *(float4*)(a8)     = *(const float4*)&At[rA * BK + ((cg0 ^ n4) << 2)];
            *(float4*)(a8 + 4) = *(const float4*)&At[rA * BK + (((cg0 + 1) ^ n4) << 2)];
            *(float4*)(w8)     = *(const float4*)&Wt[n4 * BK + ((cg0 ^ n4) << 2)];
            *(float4*)(w8 + 4) = *(const float4*)&Wt[n4 * BK + (((cg0 + 1) ^ n4) << 2)];
            bf16x8 ah, al, wh, wl;
            split8t(a8, ah, al);
            split8t(w8, wh, wl);
            acc = mfma16(ah, wh, acc);
            acc = mfma16(al, wh, acc);
            acc = mfma16(ah, wl, acc);
        }
        __syncthreads();   // protect LDS from next chunk's staging
    }
    #pragma unroll
    for (int r = 0; r < 4; ++r){
        u16 tj = tbl[lane * 4 + r];
        tout[r] = w * 16 + (tj & 15);
        jout[r] = (tj >> 8) & 15;
    }
}

// stage GEMM: grid = 128 jt x KQ; partial out Pout[kq][64][DIM]
__global__ __launch_bounds__(256)
void gemm4(const float* __restrict__ A, const float* __restrict__ W,
           const u16* __restrict__ tbl, float* __restrict__ Pout)
{
    __shared__ float At[64 * BK];
    __shared__ float Wt[16 * BK];
    const int kq = blockIdx.x & (KQ - 1);
    const int j0 = (blockIdx.x >> 2) * 16;
    f32x4 acc; int tr[4], jr[4];
    gemm_body(A, W + (size_t)j0 * DIM, kq, At, Wt, tbl, acc, tr, jr);
    float* outb = Pout + (size_t)kq * FB;
    #pragma unroll
    for (int r = 0; r < 4; ++r)
        outb[(size_t)tr[r] * DIM + j0 + jr[r]] = acc[r];
}

// heads GEMM: grid = (128 We + 128 Wad + 16 Wa) x KQ = 1088
__global__ __launch_bounds__(256)
void gemm4h(const float* __restrict__ G,
            const float* __restrict__ We, const float* __restrict__ Wad,
            const float* __restrict__ Wa, const u16* __restrict__ tbl,
            float* __restrict__ PpE, float* __restrict__ PpA, float* __restrict__ PpL)
{
    __shared__ float At[64 * BK];
    __shared__ float Wt[16 * BK];
    const int kq = blockIdx.x & (KQ - 1);
    const int jt = blockIdx.x >> 2;
    const float* W; float* out; int j0, NJ;
    if (jt < 128)      { W = We;  out = PpE; j0 = jt * 16;         NJ = DIM; }
    else if (jt < 256) { W = Wad; out = PpA; j0 = (jt - 128) * 16; NJ = DIM; }
    else               { W = Wa;  out = PpL; j0 = (jt - 256) * 16; NJ = SLOTS; }
    f32x4 acc; int tr[4], jr[4];
    gemm_body(G, W + (size_t)j0 * DIM, kq, At, Wt, tbl, acc, tr, jr);
    float* outb = out + (size_t)kq * 64 * NJ;
    #pragma unroll
    for (int r = 0; r < 4; ++r)
        outb[(size_t)tr[r] * NJ + j0 + jr[r]] = acc[r];
}

// ---------------- combine partials + bias + activation ----------------
// MODE 0: relu   1: plain   2: sigmoid(v)*sigmoid(ps(t)*vw+vb)   3: X*sigmoid(v)   4: sigmoid
template<int MODE>
__global__ __launch_bounds__(256)
void comb(const float* __restrict__ P, const float* __restrict__ bias,
          const float* __restrict__ vw, const float* __restrict__ vb,
          const float* __restrict__ X, float* __restrict__ out)
{
    const size_t i0 = ((size_t)blockIdx.x * 256 + threadIdx.x) * 8;
    const int t = (int)(i0 >> 11);
    const int j = (int)(i0 & (DIM - 1));
    float v[8], tmp[8];
    *(float4*)(v)     = *(const float4*)(P + i0);
    *(float4*)(v + 4) = *(const float4*)(P + i0 + 4);
    #pragma unroll
    for (int p = 1; p < KQ; ++p){
        *(float4*)(tmp)     = *(const float4*)(P + (size_t)p * FB + i0);
        *(float4*)(tmp + 4) = *(const float4*)(P + (size_t)p * FB + i0 + 4);
        #pragma unroll
        for (int c = 0; c < 8; ++c) v[c] += tmp[c];
    }
    float b8[8];
    *(float4*)(b8)     = *(const float4*)(bias + j);
    *(float4*)(b8 + 4) = *(const float4*)(bias + j + 4);
    float x8[8], y8[8];
    if (MODE == 2){
        *(float4*)(x8)     = *(const float4*)(vw + j);
        *(float4*)(x8 + 4) = *(const float4*)(vw + j + 4);
        *(float4*)(y8)     = *(const float4*)(vb + j);
        *(float4*)(y8 + 4) = *(const float4*)(vb + j + 4);
    }
    if (MODE == 3){
        *(float4*)(x8)     = *(const float4*)(X + i0);
        *(float4*)(x8 + 4) = *(const float4*)(X + i0 + 4);
    }
    const float ps = -cosf(0.37699111843077515f * (float)(t + 1));
    float r[8];
    #pragma unroll
    for (int c = 0; c < 8; ++c){
        float u = v[c] + b8[c];
        if (MODE == 0)      r[c] = fmaxf(u, 0.f);
        else if (MODE == 1) r[c] = u;
        else if (MODE == 2) r[c] = sigmoidf_(u) * sigmoidf_(fmaf(ps, x8[c], y8[c]));
        else if (MODE == 3) r[c] = x8[c] * sigmoidf_(u);
        else                r[c] = sigmoidf_(u);
    }
    *(float4*)(out + i0)     = *(const float4*)(r);
    *(float4*)(out + i0 + 4) = *(const float4*)(r + 4);
}

// ---------------- sequential softmax/usage scan (sums 4 logit partials + ba) -------------
__global__ void scan_k(const float* __restrict__ PpL, const float* __restrict__ ba,
                       const float* __restrict__ usage0, float* __restrict__ wgt)
{
    const int lane = threadIdx.x;   // 1 wave, 4 slots/lane
    float u[4], bv[4];
    #pragma unroll
    for (int c = 0; c < 4; ++c){ u[c] = usage0[lane + 64 * c]; bv[c] = ba[lane + 64 * c]; }
    const int PS = TSTEPS * SLOTS;
    for (int t = 0; t < TSTEPS; ++t){
        float e[4];
        #pragma unroll
        for (int c = 0; c < 4; ++c){
            int s = lane + 64 * c;
            float lg = PpL[t * SLOTS + s] + PpL[PS + t * SLOTS + s]
                     + PpL[2 * PS + t * SLOTS + s] + PpL[3 * PS + t * SLOTS + s] + bv[c];
            e[c] = __expf(lg - 0.1f * u[c]);
        }
        float sm = (e[0] + e[1]) + (e[2] + e[3]);
        #pragma unroll
        for (int off = 1; off < 64; off <<= 1) sm += __shfl_xor(sm, off, 64);
        float inv = 1.0f / sm;
        float* wr = wgt + t * SLOTS;
        #pragma unroll
        for (int c = 0; c < 4; ++c){
            float ww = e[c] * inv;
            u[c] += ww;
            wr[lane + 64 * c] = ww;
        }
    }
}

// ---------------- memory recurrence ----------------
__global__ __launch_bounds__(256)
void mem_k(const float* __restrict__ mem0, const float* __restrict__ wgt,
           const float* __restrict__ ER, const float* __restrict__ AD,
           float* __restrict__ out)
{
    const int s = threadIdx.x;
    const int d0 = blockIdx.x * 8;
    float m[8];
    *(float4*)(m)     = *(const float4*)(mem0 + (size_t)s * DIM + d0);
    *(float4*)(m + 4) = *(const float4*)(mem0 + (size_t)s * DIM + d0 + 4);
    for (int t = 0; t < TSTEPS; ++t){
        const size_t ro = (size_t)t * DIM + d0;
        float e8[8], a8[8];
        *(float4*)(e8)     = *(const float4*)(ER + ro);
        *(float4*)(e8 + 4) = *(const float4*)(ER + ro + 4);
        *(float4*)(a8)     = *(const float4*)(AD + ro);
        *(float4*)(a8 + 4) = *(const float4*)(AD + ro + 4);
        float w = 0.5f * wgt[t * SLOTS + s];
        #pragma unroll
        for (int c = 0; c < 8; ++c){
            float f = w * e8[c];
            float tmp = fmaf(-f, m[c], m[c]);
            m[c] = fmaf(w, a8[c], tmp);
        }
    }
    float* op = out + (size_t)s * DIM + d0;
    *(float4*)(op)     = *(const float4*)(m);
    *(float4*)(op + 4) = *(const float4*)(m + 4);
}

extern "C" void kernel_launch(void* const* d_in, const int* in_sizes, int n_in,
                              void* d_out, int out_size, void* d_ws, size_t ws_size,
                              hipStream_t stream)
{
    const float* traces = (const float*)d_in[0];
    const float* noise  = (const float*)d_in[1];
    const float* mem0   = (const float*)d_in[2];
    const float* usage0 = (const float*)d_in[3];
    const float* W1 = (const float*)d_in[4];  const float* b1 = (const float*)d_in[5];
    const float* W2 = (const float*)d_in[6];  const float* b2 = (const float*)d_in[7];
    const float* Wl = (const float*)d_in[8];  const float* bl = (const float*)d_in[9];
    const float* vw = (const float*)d_in[10]; const float* vb = (const float*)d_in[11];
    const float* Wg = (const float*)d_in[12]; const float* bg = (const float*)d_in[13];
    const float* Wa = (const float*)d_in[14]; const float* ba = (const float*)d_in[15];
    const float* We = (const float*)d_in[16]; const float* be = (const float*)d_in[17];
    const float* Wad = (const float*)d_in[18]; const float* bad_ = (const float*)d_in[19];
    const int* idx = (const int*)d_in[20];

    char* ws = (char*)d_ws;
    int* FLAGS = (int*)ws;
    u16* TBL = (u16*)(ws + 16);
    float* pool = (float*)(ws + 1024);
    // layout (units of FB floats):
    // [0] A0  [1] H  [2] X  [3] LV  [4] G  [5] ER  [6] AD  [7..10] Pp (stage partials)
    // heads: PpE aliases [0..3] (A0,H,X,LV dead by then), PpA aliases [7..10],
    // PpL at [11] (4*64*256 floats), WG after it.
    float* A0v = pool;
    float* Hv  = pool + 1 * FB;
    float* Xv  = pool + 2 * FB;
    float* LVv = pool + 3 * FB;
    float* Gv  = pool + 4 * FB;
    float* ERv = pool + 5 * FB;
    float* ADv = pool + 6 * FB;
    float* Pp  = pool + 7 * FB;                  // 4*FB
    float* PpE = pool;                           // 4*FB alias over A0,H,X,LV
    float* PpA = Pp;                             // 4*FB alias
    float* PpL = pool + 11 * FB;                 // 4*64*256
    float* WGv = PpL + 4 * TSTEPS * SLOTS;       // 64*256

    detect_k<<<1, 256, 0, stream>>>(idx, FLAGS);
    calib_k<<<1, 64, 0, stream>>>(TBL);
    prep<<<TSTEPS, 256, 0, stream>>>(traces, noise, idx, FLAGS, A0v);

    gemm4<<<128 * KQ, 256, 0, stream>>>(A0v, W1, TBL, Pp);
    comb<0><<<64, 256, 0, stream>>>(Pp, b1, nullptr, nullptr, nullptr, Hv);
    gemm4<<<128 * KQ, 256, 0, stream>>>(Hv, W2, TBL, Pp);
    comb<1><<<64, 256, 0, stream>>>(Pp, b2, nullptr, nullptr, nullptr, Xv);
    gemm4<<<128 * KQ, 256, 0, stream>>>(Xv, Wl, TBL, Pp);
    comb<2><<<64, 256, 0, stream>>>(Pp, bl, vw, vb, nullptr, LVv);
    gemm4<<<128 * KQ, 256, 0, stream>>>(LVv, Wg, TBL, Pp);
    comb<3><<<64, 256, 0, stream>>>(Pp, bg, nullptr, nullptr, Xv, Gv);

    gemm4h<<<272 * KQ, 256, 0, stream>>>(Gv, We, Wad, Wa, TBL, PpE, PpA, PpL);
    comb<4><<<64, 256, 0, stream>>>(PpE, be, nullptr, nullptr, nullptr, ERv);
    comb<1><<<64, 256, 0, stream>>>(PpA, bad_, nullptr, nullptr, nullptr, ADv);

    scan_k<<<1, 64, 0, stream>>>(PpL, ba, usage0, WGv);
    mem_k<<<DIM / 8, 256, 0, stream>>>(mem0, WGv, ERv, ADv, (float*)d_out);
}